// Round 3
// baseline (62.697 us; speedup 1.0000x reference)
//
#include <hip/hip_runtime.h>

// B=2, N=512, C_IN=16, C_OUT=16, HID=64
#define NQ   512
#define CI   16
#define CO   16
#define HIDN 64

// ---------------------------------------------------------------------------
// Kernel 1 (per zb): M[zb][i*64+h] = sum_j f[zb][j] * W2[(i*16+j)*64 + h]
//                    C[zb][i]      = sum_j f[zb][j] * b2[i*16+j]
// ---------------------------------------------------------------------------
__global__ __launch_bounds__(256) void compute_M_kernel(
    const float* __restrict__ features,   // [1024,16]
    const float* __restrict__ W2,         // [256,64]
    const float* __restrict__ b2,         // [256]
    float* __restrict__ Mws,              // [1024][1024]
    float* __restrict__ Cws)              // [1024][16]
{
    const int zb  = blockIdx.x;
    const int tid = threadIdx.x;

    // f is block-uniform -> compiler scalarizes to s_load
    float f[CI];
    #pragma unroll
    for (int j = 0; j < CI; ++j) f[j] = features[zb * CI + j];

    #pragma unroll
    for (int e = 0; e < 4; ++e) {
        int idx = tid + e * 256;        // 0..1023
        int i   = idx >> 6;             // C_OUT index
        int hh  = idx & 63;             // HID index (consecutive across lanes -> coalesced W2 reads)
        float acc = 0.f;
        #pragma unroll
        for (int j = 0; j < CI; ++j)
            acc = fmaf(f[j], W2[(i * CI + j) * HIDN + hh], acc);
        Mws[(size_t)zb * 1024 + idx] = acc;
    }
    if (tid < CO) {
        float acc = 0.f;
        #pragma unroll
        for (int j = 0; j < CI; ++j)
            acc = fmaf(f[j], b2[tid * CI + j], acc);
        Cws[zb * CO + tid] = acc;
    }
}

// ---------------------------------------------------------------------------
// Kernel 2: one thread per 'a'. Zero LDS, zero syncthreads.
// All W1/b1/M/C accesses are wave-uniform with compile-time indices ->
// scalar loads; contraction is v_fma v,v,s,v.
// hv is computed in chunks of 16 so the live set stays ~50 VGPR (no spill).
// ---------------------------------------------------------------------------
__global__ __launch_bounds__(256) void apply_pairconv_kernel(
    const float* __restrict__ geometry,   // [1024,3]
    const float* __restrict__ W1,         // [64,4]
    const float* __restrict__ b1,         // [64]
    const float* __restrict__ Mws,        // [1024][1024]
    const float* __restrict__ Cws,        // [1024][16]
    float* __restrict__ out)              // [2,512,512,16]
{
    const int bid = blockIdx.x;
    const int zb  = bid >> 1;            // z*512 + b
    const int a0  = (bid & 1) << 8;
    const int z   = zb >> 9;
    const int b   = zb & 511;
    const int tid = threadIdx.x;
    const int a   = a0 + tid;

    // gb is block-uniform -> scalar; ga is per-thread -> vector
    const float* ga = geometry + (size_t)(z * NQ + a) * 3;
    const float* gb = geometry + (size_t)(z * NQ + b) * 3;
    const float rx = gb[0] - ga[0];
    const float ry = gb[1] - ga[1];
    const float rz = gb[2] - ga[2];
    const float nrm = sqrtf(fmaf(rx, rx, fmaf(ry, ry, rz * rz)) + 1e-12f);

    float o[CO];
    const float* Cz = Cws + zb * CO;
    #pragma unroll
    for (int i = 0; i < CO; ++i) o[i] = Cz[i];

    const float* Mzb = Mws + (size_t)zb * 1024;

    #pragma unroll 1
    for (int c = 0; c < 4; ++c) {
        // ---- hv chunk: h = c*16 .. c*16+15 ----
        float hvc[16];
        #pragma unroll
        for (int kk = 0; kk < 16; ++kk) {
            const int h = c * 16 + kk;
            float x = b1[h];
            x = fmaf(rx,  W1[h * 4 + 0], x);
            x = fmaf(ry,  W1[h * 4 + 1], x);
            x = fmaf(rz,  W1[h * 4 + 2], x);
            x = fmaf(nrm, W1[h * 4 + 3], x);
            // gelu (tanh approx, sigmoid form): x * sigmoid(2u), u = sqrt(2/pi)(x+0.044715x^3)
            float x2 = x * x;
            float q  = fmaf(x2, 0.044715f, 1.0f);
            float e  = __builtin_amdgcn_exp2f((-2.3022082f * x) * q);  // exp(-2u)
            hvc[kk]  = x * __builtin_amdgcn_rcpf(1.0f + e);
        }
        // ---- contraction against this h-chunk of all 16 M rows ----
        #pragma unroll
        for (int i = 0; i < CO; ++i) {
            const float* mi = Mzb + i * HIDN + c * 16;
            #pragma unroll
            for (int k = 0; k < 16; ++k)
                o[i] = fmaf(hvc[k], mi[k], o[i]);
        }
    }

    float* op = out + (((size_t)(z * NQ + a) * NQ) + b) * CO;
    #pragma unroll
    for (int i = 0; i < CO; i += 4)
        *reinterpret_cast<float4*>(op + i) = make_float4(o[i], o[i+1], o[i+2], o[i+3]);
}

// ---------------------------------------------------------------------------
// Fallback (round-1 proven kernel) if ws_size is too small.
// ---------------------------------------------------------------------------
__global__ __launch_bounds__(256) void fused_pairconv_kernel(
    const float* __restrict__ features, const float* __restrict__ geometry,
    const float* __restrict__ W1, const float* __restrict__ b1,
    const float* __restrict__ W2, const float* __restrict__ b2,
    float* __restrict__ out)
{
    __shared__ float M_sm[CO * HIDN];
    __shared__ float c_sm[CO];
    __shared__ float f_sm[CI];
    __shared__ float W1_sm[HIDN * 4];
    __shared__ float b1_sm[HIDN];

    const int bid = blockIdx.x;
    const int zb  = bid >> 1;
    const int a0  = (bid & 1) << 8;
    const int z   = zb >> 9;
    const int tid = threadIdx.x;

    W1_sm[tid] = W1[tid];
    if (tid < HIDN) b1_sm[tid] = b1[tid];
    if (tid < CI)   f_sm[tid]  = features[zb * CI + tid];
    __syncthreads();

    #pragma unroll
    for (int e = 0; e < 4; ++e) {
        int idx = tid + e * 256;
        int i = idx >> 6, hh = idx & 63;
        float acc = 0.f;
        #pragma unroll
        for (int j = 0; j < CI; ++j)
            acc = fmaf(f_sm[j], W2[(i * CI + j) * HIDN + hh], acc);
        M_sm[idx] = acc;
    }
    if (tid < CO) {
        float acc = 0.f;
        #pragma unroll
        for (int j = 0; j < CI; ++j)
            acc = fmaf(f_sm[j], b2[tid * CI + j], acc);
        c_sm[tid] = acc;
    }
    __syncthreads();

    const int a = a0 + tid;
    const float* ga = geometry + (size_t)(z * NQ + a) * 3;
    const float* gb = geometry + (size_t)(z * NQ + (zb & 511)) * 3;
    const float rx = gb[0] - ga[0];
    const float ry = gb[1] - ga[1];
    const float rz = gb[2] - ga[2];
    const float nrm = sqrtf(fmaf(rx, rx, fmaf(ry, ry, rz * rz)) + 1e-12f);

    float hv[HIDN];
    #pragma unroll
    for (int k = 0; k < HIDN; ++k) {
        float x = b1_sm[k];
        x = fmaf(rx,  W1_sm[k * 4 + 0], x);
        x = fmaf(ry,  W1_sm[k * 4 + 1], x);
        x = fmaf(rz,  W1_sm[k * 4 + 2], x);
        x = fmaf(nrm, W1_sm[k * 4 + 3], x);
        float x2 = x * x;
        float q  = fmaf(x2, 0.044715f, 1.0f);
        float e  = __builtin_amdgcn_exp2f((-2.3022082f * x) * q);
        hv[k] = x * __builtin_amdgcn_rcpf(1.0f + e);
    }

    float o[CO];
    #pragma unroll
    for (int i = 0; i < CO; ++i) o[i] = c_sm[i];
    #pragma unroll
    for (int i = 0; i < CO; ++i) {
        #pragma unroll
        for (int k = 0; k < HIDN; k += 4) {
            const float4 m4 = *reinterpret_cast<const float4*>(&M_sm[i * HIDN + k]);
            o[i] = fmaf(hv[k + 0], m4.x, o[i]);
            o[i] = fmaf(hv[k + 1], m4.y, o[i]);
            o[i] = fmaf(hv[k + 2], m4.z, o[i]);
            o[i] = fmaf(hv[k + 3], m4.w, o[i]);
        }
    }

    float* op = out + (((size_t)(z * NQ + a) * NQ) + (zb & 511)) * CO;
    #pragma unroll
    for (int i = 0; i < CO; i += 4)
        *reinterpret_cast<float4*>(op + i) = make_float4(o[i], o[i+1], o[i+2], o[i+3]);
}

extern "C" void kernel_launch(void* const* d_in, const int* in_sizes, int n_in,
                              void* d_out, int out_size, void* d_ws, size_t ws_size,
                              hipStream_t stream) {
    const float* features = (const float*)d_in[0];
    const float* geometry = (const float*)d_in[1];
    const float* W1       = (const float*)d_in[2];
    const float* b1       = (const float*)d_in[3];
    const float* W2       = (const float*)d_in[4];
    const float* b2       = (const float*)d_in[5];
    float* out = (float*)d_out;

    const size_t needM = (size_t)1024 * 1024 * sizeof(float);   // 4 MB
    const size_t needC = (size_t)1024 * CO * sizeof(float);     // 64 KB
    if (ws_size >= needM + needC) {
        float* Mws = (float*)d_ws;
        float* Cws = (float*)d_ws + (size_t)1024 * 1024;
        compute_M_kernel<<<1024, 256, 0, stream>>>(features, W2, b2, Mws, Cws);
        apply_pairconv_kernel<<<2048, 256, 0, stream>>>(
            geometry, W1, b1, Mws, Cws, out);
    } else {
        fused_pairconv_kernel<<<2048, 256, 0, stream>>>(
            features, geometry, W1, b1, W2, b2, out);
    }
}

// Round 4
// 30.278 us; speedup vs baseline: 2.0707x; 2.0707x over previous
//
#include <hip/hip_runtime.h>

// B=2, N=512, C_IN=16, C_OUT=16, HID=64
#define NQ   512
#define CI   16
#define CO   16
#define HIDN 64

typedef __attribute__((ext_vector_type(8))) short bf16x8;
typedef __attribute__((ext_vector_type(4))) float f32x4;

__device__ __forceinline__ unsigned short f32_to_bf16_rne(float v) {
    unsigned u = __builtin_bit_cast(unsigned, v);
    u += 0x7fffu + ((u >> 16) & 1u);
    return (unsigned short)(u >> 16);
}

// ---------------------------------------------------------------------------
// Kernel 1 (per zb):
//   M[i][h] = sum_j f[j] * W2[(i*16+j)*64 + h]  -> bf16 hi/lo split
//   Mbf layout: [zb][part(0=hi,1=lo)][i(16)][k(64)] ushort   (2048/zb)
//   Cws[zb][i] = sum_j f[j] * b2[i*16+j]                      (f32)
// ---------------------------------------------------------------------------
__global__ __launch_bounds__(256) void compute_M_kernel(
    const float* __restrict__ features,   // [1024,16]
    const float* __restrict__ W2,         // [256,64]
    const float* __restrict__ b2,         // [256]
    unsigned short* __restrict__ Mbf,     // [1024][2][16][64]
    float* __restrict__ Cws)              // [1024][16]
{
    const int zb  = blockIdx.x;
    const int tid = threadIdx.x;

    float f[CI];
    #pragma unroll
    for (int j = 0; j < CI; ++j) f[j] = features[zb * CI + j];

    #pragma unroll
    for (int e = 0; e < 4; ++e) {
        int idx = tid + e * 256;        // 0..1023 = i*64 + k
        int i   = idx >> 6;
        int k   = idx & 63;
        float acc = 0.f;
        #pragma unroll
        for (int j = 0; j < CI; ++j)
            acc = fmaf(f[j], W2[(i * CI + j) * HIDN + k], acc);
        unsigned short hi = f32_to_bf16_rne(acc);
        float hf = __builtin_bit_cast(float, (unsigned)hi << 16);
        unsigned short lo = f32_to_bf16_rne(acc - hf);
        Mbf[(size_t)zb * 2048 + idx]        = hi;
        Mbf[(size_t)zb * 2048 + 1024 + idx] = lo;
    }
    if (tid < CO) {
        float acc = 0.f;
        #pragma unroll
        for (int j = 0; j < CI; ++j)
            acc = fmaf(f[j], b2[tid * CI + j], acc);
        Cws[zb * CO + tid] = acc;
    }
}

// ---------------------------------------------------------------------------
// Kernel 2: MFMA contraction. Each wave owns 64 'a' (4 tiles of 16).
// Lane l: col = l&15 (= output i, and = row a within tile), g = l>>4.
// A-frag computed in-place: lane holds hv[a=col][h = kc*32 + g*8 + j].
// B-frag: Mbf[zb][part][i=col][k], 16B vector load per (part,kc).
// acc = mfma(Ah, Bhi) + mfma(Ah, Blo)  -> M rounding fully compensated.
// ---------------------------------------------------------------------------
__global__ __launch_bounds__(256) void apply_mfma_kernel(
    const float* __restrict__ geometry,        // [1024,3]
    const float* __restrict__ W1,              // [64,4]
    const float* __restrict__ b1,              // [64]
    const unsigned short* __restrict__ Mbf,    // [1024][2][16][64]
    const float* __restrict__ Cws,             // [1024][16]
    float* __restrict__ out)                   // [2,512,512,16]
{
    const int bid  = blockIdx.x;
    const int zb   = bid >> 1;            // z*512 + b
    const int a0   = (bid & 1) << 8;
    const int z    = zb >> 9;
    const int b    = zb & 511;
    const int tid  = threadIdx.x;
    const int wv   = tid >> 6;
    const int lane = tid & 63;
    const int col  = lane & 15;
    const int g    = lane >> 4;

    // B fragments (block-constant, 4 x 16B loads)
    const unsigned short* Mz = Mbf + (size_t)zb * 2048;
    bf16x8 Bf[2][2];   // [part][kc]
    #pragma unroll
    for (int part = 0; part < 2; ++part)
        #pragma unroll
        for (int kc = 0; kc < 2; ++kc)
            Bf[part][kc] = *reinterpret_cast<const bf16x8*>(
                Mz + part * 1024 + col * 64 + kc * 32 + g * 8);

    const float cinit = Cws[zb * CO + col];
    f32x4 acc[4];
    #pragma unroll
    for (int t = 0; t < 4; ++t) acc[t] = (f32x4){cinit, cinit, cinit, cinit};

    const float gbx = geometry[(z * NQ + b) * 3 + 0];
    const float gby = geometry[(z * NQ + b) * 3 + 1];
    const float gbz = geometry[(z * NQ + b) * 3 + 2];

    const int abase = a0 + wv * 64;

    // rel/nrm per tile (a = abase + t*16 + col; identical across g-groups, as
    // required by the A-fragment layout: row is determined by l&15 only)
    float rel[4][4];
    #pragma unroll
    for (int t = 0; t < 4; ++t) {
        const float* ga = geometry + (size_t)(z * NQ + abase + t * 16 + col) * 3;
        float rx = gbx - ga[0], ry = gby - ga[1], rz = gbz - ga[2];
        rel[t][0] = rx; rel[t][1] = ry; rel[t][2] = rz;
        rel[t][3] = sqrtf(fmaf(rx, rx, fmaf(ry, ry, rz * rz)) + 1e-12f);
    }

    #pragma unroll
    for (int kc = 0; kc < 2; ++kc) {
        // W1 rows for this lane's h-slice (hoisted across the 4 tiles)
        float4 w[8]; float bb[8];
        #pragma unroll
        for (int j = 0; j < 8; ++j) {
            int h = kc * 32 + g * 8 + j;
            w[j]  = *reinterpret_cast<const float4*>(W1 + h * 4);
            bb[j] = b1[h];
        }
        #pragma unroll
        for (int t = 0; t < 4; ++t) {
            bf16x8 Ah;
            #pragma unroll
            for (int j = 0; j < 8; ++j) {
                float x = bb[j];
                x = fmaf(rel[t][0], w[j].x, x);
                x = fmaf(rel[t][1], w[j].y, x);
                x = fmaf(rel[t][2], w[j].z, x);
                x = fmaf(rel[t][3], w[j].w, x);
                // gelu(tanh approx, sigmoid form): x * sigmoid(2*sqrt(2/pi)*(x+0.044715x^3))
                float q  = fmaf(x * x, 0.044715f, 1.0f);
                float e  = __builtin_amdgcn_exp2f((-2.3022082f * x) * q);
                float hv = x * __builtin_amdgcn_rcpf(1.0f + e);
                Ah[j] = (short)f32_to_bf16_rne(hv);
            }
            acc[t] = __builtin_amdgcn_mfma_f32_16x16x32_bf16(Ah, Bf[0][kc], acc[t], 0, 0, 0);
            acc[t] = __builtin_amdgcn_mfma_f32_16x16x32_bf16(Ah, Bf[1][kc], acc[t], 0, 0, 0);
        }
    }

    // epilogue: D[row][col], row = g*4 + r
    #pragma unroll
    for (int t = 0; t < 4; ++t) {
        #pragma unroll
        for (int r = 0; r < 4; ++r) {
            int arow = abase + t * 16 + g * 4 + r;
            out[(((size_t)(z * NQ + arow)) * NQ + b) * CO + col] = acc[t][r];
        }
    }
}

// ---------------------------------------------------------------------------
// Fallback (round-1 proven kernel) if ws_size is too small.
// ---------------------------------------------------------------------------
__global__ __launch_bounds__(256) void fused_pairconv_kernel(
    const float* __restrict__ features, const float* __restrict__ geometry,
    const float* __restrict__ W1, const float* __restrict__ b1,
    const float* __restrict__ W2, const float* __restrict__ b2,
    float* __restrict__ out)
{
    __shared__ float M_sm[CO * HIDN];
    __shared__ float c_sm[CO];
    __shared__ float f_sm[CI];
    __shared__ float W1_sm[HIDN * 4];
    __shared__ float b1_sm[HIDN];

    const int bid = blockIdx.x;
    const int zb  = bid >> 1;
    const int a0  = (bid & 1) << 8;
    const int z   = zb >> 9;
    const int tid = threadIdx.x;

    W1_sm[tid] = W1[tid];
    if (tid < HIDN) b1_sm[tid] = b1[tid];
    if (tid < CI)   f_sm[tid]  = features[zb * CI + tid];
    __syncthreads();

    #pragma unroll
    for (int e = 0; e < 4; ++e) {
        int idx = tid + e * 256;
        int i = idx >> 6, hh = idx & 63;
        float acc = 0.f;
        #pragma unroll
        for (int j = 0; j < CI; ++j)
            acc = fmaf(f_sm[j], W2[(i * CI + j) * HIDN + hh], acc);
        M_sm[idx] = acc;
    }
    if (tid < CO) {
        float acc = 0.f;
        #pragma unroll
        for (int j = 0; j < CI; ++j)
            acc = fmaf(f_sm[j], b2[tid * CI + j], acc);
        c_sm[tid] = acc;
    }
    __syncthreads();

    const int a = a0 + tid;
    const float* ga = geometry + (size_t)(z * NQ + a) * 3;
    const float* gb = geometry + (size_t)(z * NQ + (zb & 511)) * 3;
    const float rx = gb[0] - ga[0];
    const float ry = gb[1] - ga[1];
    const float rz = gb[2] - ga[2];
    const float nrm = sqrtf(fmaf(rx, rx, fmaf(ry, ry, rz * rz)) + 1e-12f);

    float hv[HIDN];
    #pragma unroll
    for (int k = 0; k < HIDN; ++k) {
        float x = b1_sm[k];
        x = fmaf(rx,  W1_sm[k * 4 + 0], x);
        x = fmaf(ry,  W1_sm[k * 4 + 1], x);
        x = fmaf(rz,  W1_sm[k * 4 + 2], x);
        x = fmaf(nrm, W1_sm[k * 4 + 3], x);
        float x2 = x * x;
        float q  = fmaf(x2, 0.044715f, 1.0f);
        float e  = __builtin_amdgcn_exp2f((-2.3022082f * x) * q);
        hv[k] = x * __builtin_amdgcn_rcpf(1.0f + e);
    }

    float o[CO];
    #pragma unroll
    for (int i = 0; i < CO; ++i) o[i] = c_sm[i];
    #pragma unroll
    for (int i = 0; i < CO; ++i) {
        #pragma unroll
        for (int k = 0; k < HIDN; k += 4) {
            const float4 m4 = *reinterpret_cast<const float4*>(&M_sm[i * HIDN + k]);
            o[i] = fmaf(hv[k + 0], m4.x, o[i]);
            o[i] = fmaf(hv[k + 1], m4.y, o[i]);
            o[i] = fmaf(hv[k + 2], m4.z, o[i]);
            o[i] = fmaf(hv[k + 3], m4.w, o[i]);
        }
    }

    float* op = out + (((size_t)(z * NQ + a) * NQ) + (zb & 511)) * CO;
    #pragma unroll
    for (int i = 0; i < CO; i += 4)
        *reinterpret_cast<float4*>(op + i) = make_float4(o[i], o[i+1], o[i+2], o[i+3]);
}

extern "C" void kernel_launch(void* const* d_in, const int* in_sizes, int n_in,
                              void* d_out, int out_size, void* d_ws, size_t ws_size,
                              hipStream_t stream) {
    const float* features = (const float*)d_in[0];
    const float* geometry = (const float*)d_in[1];
    const float* W1       = (const float*)d_in[2];
    const float* b1       = (const float*)d_in[3];
    const float* W2       = (const float*)d_in[4];
    const float* b2       = (const float*)d_in[5];
    float* out = (float*)d_out;

    const size_t needM = (size_t)1024 * 2048 * sizeof(unsigned short); // 4 MB
    const size_t needC = (size_t)1024 * CO * sizeof(float);            // 64 KB
    if (ws_size >= needM + needC) {
        unsigned short* Mbf = (unsigned short*)d_ws;
        float* Cws = (float*)((char*)d_ws + needM);
        compute_M_kernel<<<1024, 256, 0, stream>>>(features, W2, b2, Mbf, Cws);
        apply_mfma_kernel<<<2048, 256, 0, stream>>>(
            geometry, W1, b1, Mbf, Cws, out);
    } else {
        fused_pairconv_kernel<<<2048, 256, 0, stream>>>(
            features, geometry, W1, b1, W2, b2, out);
    }
}

// Round 5
// 25.258 us; speedup vs baseline: 2.4822x; 1.1987x over previous
//
#include <hip/hip_runtime.h>

// B=2, N=512, C_IN=16, C_OUT=16, HID=64
#define NQ   512
#define CI   16
#define CO   16
#define HIDN 64

typedef __attribute__((ext_vector_type(8))) short bf16x8;
typedef __attribute__((ext_vector_type(4))) float f32x4;

// packed bf16 convert: low16 = bf16(a), high16 = bf16(b)
__device__ __forceinline__ unsigned cvt_pk_bf16(float a, float b) {
    unsigned r;
    asm("v_cvt_pk_bf16_f32 %0, %1, %2" : "=v"(r) : "v"(a), "v"(b));
    return r;
}

// ---------------------------------------------------------------------------
// One block per zb (z*512+b), 512 threads = 8 waves, each wave owns 64 'a'.
//
//   M[i][h] = sum_j f[j]*W2[(i*16+j)*64+h]   (f32 in LDS, padded rows)
//   c[i]    = sum_j f[j]*b2[i*16+j]
//   out[a,b,i] = sum_h gelu(W1·[rel,|rel|]+b1)[a,h] * M[i][h] + c[i]
//
// Contraction via mfma_f32_16x16x32_bf16: A = hv (built in-register directly
// in fragment layout), B = M in bf16 hi/lo split (error-compensated),
// C-term folded into accumulator init.
// ---------------------------------------------------------------------------
__global__ __launch_bounds__(512) void fused_mfma_kernel(
    const float* __restrict__ features,   // [1024,16]
    const float* __restrict__ geometry,   // [1024,3]
    const float* __restrict__ W1,         // [64,4]
    const float* __restrict__ b1,         // [64]
    const float* __restrict__ W2,         // [256,64]
    const float* __restrict__ b2,         // [256]
    float* __restrict__ out)              // [2,512,512,16]
{
    __shared__ float M_sm[CO][68];   // +4 pad: stride-272B reads -> <=2-way (free)
    __shared__ float c_sm[CO];

    const int zb  = blockIdx.x;          // z*512 + b
    const int z   = zb >> 9;
    const int b   = zb & 511;
    const int tid = threadIdx.x;

    // ---- stage A: per-zb M (f32) + c into LDS ----
    float f[CI];                          // block-uniform -> scalar loads
    #pragma unroll
    for (int j = 0; j < CI; ++j) f[j] = features[zb * CI + j];

    #pragma unroll
    for (int e = 0; e < 2; ++e) {
        int idx = tid + e * 512;          // 0..1023 = i*64 + k
        int i = idx >> 6, k = idx & 63;   // lanes consecutive k -> coalesced W2
        float acc = 0.f;
        #pragma unroll
        for (int j = 0; j < CI; ++j)
            acc = fmaf(f[j], W2[(i * CI + j) * HIDN + k], acc);
        M_sm[i][k] = acc;
    }
    if (tid < CO) {
        float acc = 0.f;
        #pragma unroll
        for (int j = 0; j < CI; ++j)
            acc = fmaf(f[j], b2[tid * CI + j], acc);
        c_sm[tid] = acc;
    }
    __syncthreads();

    const int wv   = tid >> 6;
    const int lane = tid & 63;
    const int col  = lane & 15;          // A-row / B-col / D-col
    const int g    = lane >> 4;          // k-group

    // ---- B fragments: hi/lo bf16 split of M, built from LDS ----
    bf16x8 Bf[2][2];   // [part][kc]
    #pragma unroll
    for (int kc = 0; kc < 2; ++kc) {
        const float* mp = &M_sm[col][kc * 32 + g * 8];
        unsigned hpk[4], lpk[4];
        #pragma unroll
        for (int p = 0; p < 4; ++p) {
            float m0 = mp[2 * p], m1 = mp[2 * p + 1];
            unsigned h = cvt_pk_bf16(m0, m1);
            float h0 = __builtin_bit_cast(float, h << 16);
            float h1 = __builtin_bit_cast(float, h & 0xffff0000u);
            hpk[p] = h;
            lpk[p] = cvt_pk_bf16(m0 - h0, m1 - h1);
        }
        union { unsigned u[4]; bf16x8 v; } uh, ul;
        #pragma unroll
        for (int p = 0; p < 4; ++p) { uh.u[p] = hpk[p]; ul.u[p] = lpk[p]; }
        Bf[0][kc] = uh.v;
        Bf[1][kc] = ul.v;
    }

    // ---- geometry / rel per tile (row a = wv*64 + t*16 + col) ----
    const float gbx = geometry[(z * NQ + b) * 3 + 0];
    const float gby = geometry[(z * NQ + b) * 3 + 1];
    const float gbz = geometry[(z * NQ + b) * 3 + 2];
    const int abase = wv * 64;

    float rel[4][4];
    #pragma unroll
    for (int t = 0; t < 4; ++t) {
        const float* ga = geometry + (size_t)(z * NQ + abase + t * 16 + col) * 3;
        float rx = gbx - ga[0], ry = gby - ga[1], rz = gbz - ga[2];
        rel[t][0] = rx; rel[t][1] = ry; rel[t][2] = rz;
        rel[t][3] = sqrtf(fmaf(rx, rx, fmaf(ry, ry, rz * rz)) + 1e-12f);
    }

    const float cinit = c_sm[col];
    f32x4 acc[4];
    #pragma unroll
    for (int t = 0; t < 4; ++t) acc[t] = (f32x4){cinit, cinit, cinit, cinit};

    // ---- main: hv in A-fragment layout, 2 MFMAs (hi+lo) per (t,kc) ----
    #pragma unroll
    for (int kc = 0; kc < 2; ++kc) {
        float4 w[8]; float bb[8];
        #pragma unroll
        for (int j = 0; j < 8; ++j) {
            int h = kc * 32 + g * 8 + j;
            w[j]  = *reinterpret_cast<const float4*>(W1 + h * 4);
            bb[j] = b1[h];
        }
        #pragma unroll
        for (int t = 0; t < 4; ++t) {
            float hv[8];
            #pragma unroll
            for (int j = 0; j < 8; ++j) {
                float x = bb[j];
                x = fmaf(rel[t][0], w[j].x, x);
                x = fmaf(rel[t][1], w[j].y, x);
                x = fmaf(rel[t][2], w[j].z, x);
                x = fmaf(rel[t][3], w[j].w, x);
                // gelu (tanh approx, sigmoid form): x*sigmoid(2*sqrt(2/pi)*(x+0.044715x^3))
                float q = fmaf(x * x, 0.044715f, 1.0f);
                float e = __builtin_amdgcn_exp2f((-2.3022082f * x) * q);
                hv[j]   = x * __builtin_amdgcn_rcpf(1.0f + e);
            }
            union { unsigned u[4]; bf16x8 v; } ua;
            #pragma unroll
            for (int p = 0; p < 4; ++p)
                ua.u[p] = cvt_pk_bf16(hv[2 * p], hv[2 * p + 1]);
            acc[t] = __builtin_amdgcn_mfma_f32_16x16x32_bf16(ua.v, Bf[0][kc], acc[t], 0, 0, 0);
            acc[t] = __builtin_amdgcn_mfma_f32_16x16x32_bf16(ua.v, Bf[1][kc], acc[t], 0, 0, 0);
        }
    }

    // ---- epilogue: D[row][col], row = g*4 + r ----
    #pragma unroll
    for (int t = 0; t < 4; ++t) {
        #pragma unroll
        for (int r = 0; r < 4; ++r) {
            int arow = abase + t * 16 + g * 4 + r;
            out[(((size_t)(z * NQ + arow)) * NQ + b) * CO + col] = acc[t][r];
        }
    }
}

extern "C" void kernel_launch(void* const* d_in, const int* in_sizes, int n_in,
                              void* d_out, int out_size, void* d_ws, size_t ws_size,
                              hipStream_t stream) {
    const float* features = (const float*)d_in[0];
    const float* geometry = (const float*)d_in[1];
    const float* W1       = (const float*)d_in[2];
    const float* b1       = (const float*)d_in[3];
    const float* W2       = (const float*)d_in[4];
    const float* b2       = (const float*)d_in[5];
    float* out = (float*)d_out;

    fused_mfma_kernel<<<1024, 512, 0, stream>>>(
        features, geometry, W1, b1, W2, b2, out);
}